// Round 1
// 65.337 us; speedup vs baseline: 1.0152x; 1.0152x over previous
//
#include <hip/hip_runtime.h>

// Problem constants (from reference setup_inputs).
#define KBINS 161
#define TFRAMES 2000
#define KT_PAD 322048   // KBINS*TFRAMES (=322000) + 48 pad: tail-tile lanes may overread
#define NTBLK 8         // ceil(TFRAMES/256) frame-chunks for phase-1 column maxima
#define JT 4            // phase-2: j's per block (1 per wave)
#define TT 64           // phase-2: frames per block (1 per lane)

// ---------------------------------------------------------------------------
// Phase 1: per-(i,t) window prep. Writes AG[i*T+t] = (A, G) with
//   A = wide ? |m| : 1        (width-1 triangle == the delta branch!)
//   G = wide ? x/S : x        (pre-normalized source value)
// so phase 2 is the uniform, branch-free gather
//   out[j,t] = sum_i relu(A[i,t] - |j-i|) * G[i,t].
// The reference's /am^2 cancels under row normalization; S is the
// edge-truncated triangle mass, computed in closed form (no d-loop):
//   S = am + sum_{d=1}^{D} (am-d)*[(d<=i)+(d<=e)],  D = floor(am), e = K-1-i
//     = am + 2*F(0,D) - F(min(i,D),D) - F(min(e,D),D),
//   F(a,b) = sum_{d=a+1}^{b} (am-d) = (b-a)*am - (b(b+1)-a(a+1))/2.
// Also writes M1[tblk][i] = max over this 256-frame chunk of A[i,t]
// (phase-2 gather radius; no atomics, no workspace pre-init needed).
// ---------------------------------------------------------------------------
__global__ __launch_bounds__(256) void m_noise_prep_kernel(
    const float* __restrict__ m,   // (K, T, 1)
    const float* __restrict__ x,   // (1, 1, K, T)
    float2* __restrict__ AG,       // (K, T) of (A, G), +pad
    float* __restrict__ M1) {      // (NTBLK, K) column maxima of A
  const int i = blockIdx.x;
  const int tblk = blockIdx.y;
  const int t = tblk * 256 + threadIdx.x;
  const bool valid = (t < TFRAMES);

  float Av = 0.0f;  // max-reduce contribution; valid lanes always >= 1
  if (valid) {
    const float mv = m[i * TFRAMES + t];
    const float xv = x[i * TFRAMES + t];
    const float am = fabsf(mv);
    const bool wide = am > 1.0f;

    const float fD = floorf(fminf(am, (float)KBINS));  // terms d>K have cnt==0
    const float fa = fminf((float)i, fD);
    const float fb = fminf((float)(KBINS - 1 - i), fD);
    const float DD = fD * (fD + 1.0f);
    const float F0 = fD * am - 0.5f * DD;
    const float Fa = (fD - fa) * am - 0.5f * (DD - fa * (fa + 1.0f));
    const float Fb = (fD - fb) * am - 0.5f * (DD - fb * (fb + 1.0f));
    const float S = am + 2.0f * F0 - Fa - Fb;

    Av = wide ? am : 1.0f;
    const float Gv = wide ? xv / S : xv;
    AG[i * TFRAMES + t] = make_float2(Av, Gv);
  }

  // Block max of A over this (i, 256-frame chunk) -> M1.
  float rm = Av;
#pragma unroll
  for (int off = 32; off; off >>= 1) rm = fmaxf(rm, __shfl_xor(rm, off, 64));
  __shared__ float s_red[4];
  if ((threadIdx.x & 63) == 0) s_red[threadIdx.x >> 6] = rm;
  __syncthreads();
  if (threadIdx.x == 0)
    M1[tblk * KBINS + i] =
        fmaxf(fmaxf(s_red[0], s_red[1]), fmaxf(s_red[2], s_red[3]));
}

// ---------------------------------------------------------------------------
// Phase 2: gather. lane = frame (coalesced 512B float2 wave-loads, L1/L2
// resident, no LDS staging), wave = output bin j. One output per thread.
// ---------------------------------------------------------------------------
__global__ __launch_bounds__(256) void m_noise_gather_kernel(
    const float2* __restrict__ AG, const float* __restrict__ M1,
    float* __restrict__ out) {
  const int tid = threadIdx.x;
  const int j = blockIdx.x * JT + (tid >> 6);
  const int t = blockIdx.y * TT + (tid & 63);
  const int tblk = blockIdx.y >> 2;  // 64-frame tile -> 256-frame chunk

  // Gather radius for this block from phase-1 chunk maxima (161 loads total).
  float mv = (tid < KBINS) ? M1[tblk * KBINS + tid] : 0.0f;
#pragma unroll
  for (int off = 32; off; off >>= 1) mv = fmaxf(mv, __shfl_xor(mv, off, 64));
  __shared__ float s_red[4];
  if ((tid & 63) == 0) s_red[tid >> 6] = mv;
  __syncthreads();
  const float maxA =
      fmaxf(fmaxf(s_red[0], s_red[1]), fmaxf(s_red[2], s_red[3]));
  int R = (int)ceilf(maxA);  // d < am <= maxA  =>  d <= R covers all taps
  if (R < 1) R = 1;
  if (R > KBINS - 1) R = KBINS - 1;

  if (j < KBINS) {
    const int lo = (j - R > 0) ? (j - R) : 0;
    const int hi = (j + R < KBINS - 1) ? (j + R) : (KBINS - 1);
    const float2* p = AG + (size_t)lo * TFRAMES + t;  // pad absorbs t>=T lanes
    float fd = (float)(j - lo);  // signed distance j-i; |fd| is the tap offset
    float acc = 0.0f;
#pragma unroll 4
    for (int i = lo; i <= hi; ++i) {
      const float2 ag = *p;
      acc = fmaf(fmaxf(ag.x - fabsf(fd), 0.0f), ag.y, acc);
      fd -= 1.0f;
      p += TFRAMES;
    }
    if (t < TFRAMES) out[j * TFRAMES + t] = acc;  // 256B-coalesced per wave
  }
}

extern "C" void kernel_launch(void* const* d_in, const int* in_sizes, int n_in,
                              void* d_out, int out_size, void* d_ws,
                              size_t ws_size, hipStream_t stream) {
  const float* m = (const float*)d_in[0];  // (K, T, 1) fp32
  const float* x = (const float*)d_in[1];  // (1, 1, K, T) fp32
  // d_in[2] = input_length (unused by the reference math)
  float* out = (float*)d_out;              // (1, 1, K, T) fp32

  float2* AG = (float2*)d_ws;                      // 322048 float2 = 2.58 MB
  float* M1 = (float*)d_ws + 2 * (size_t)KT_PAD;   // 8*161 floats after AG

  m_noise_prep_kernel<<<dim3(KBINS, NTBLK), 256, 0, stream>>>(m, x, AG, M1);
  m_noise_gather_kernel<<<dim3((KBINS + JT - 1) / JT, (TFRAMES + TT - 1) / TT),
                          256, 0, stream>>>(AG, M1, out);
}